// Round 15
// baseline (183.845 us; speedup 1.0000x reference)
//
#include <hip/hip_runtime.h>
#include <hip/hip_bf16.h>

#define N_B 1024
#define N_ITEMS 100000
#define N_CLUSTERS 10
#define N_D 64
#define MAXT 6272            // padded tile capacity; NT <= 6260 always
#define K1B 392              // segsum blocks: 392*4 waves*64 rows = 100352
#define W2PB 1563            // w2p blocks: 1563*64 = 100032 cols
#define K3BY 96              // k3 grid: 8 x 96 = 768 = 3 blocks/CU
#define NBLK3 768
#define NGW 384              // 96 by * 4 waves; tiles/wave = 6272/384 = 16.33

typedef __attribute__((ext_vector_type(8))) short short8;
typedef __attribute__((ext_vector_type(4))) float f32x4;

#if defined(__has_builtin)
#if __has_builtin(__builtin_amdgcn_exp2f)
#define EXP2F(x) __builtin_amdgcn_exp2f(x)
#endif
#endif
#ifndef EXP2F
#define EXP2F(x) exp2f(x)
#endif

#define MFMA(a, b, c) __builtin_amdgcn_mfma_f32_16x16x32_bf16(a, b, c, 0, 0, 0)

// bf16 RNE helpers (bit-level; sign-safe)
__device__ __forceinline__ unsigned short bf16_rne(float x) {
  unsigned u = __float_as_uint(x);
  u += 0x7FFFu + ((u >> 16) & 1u);
  return (unsigned short)(u >> 16);
}

// ---------------------------------------------------------------------------
// Kernel A: blocks [0,392) = segsum + inv zero; blocks [392,1955) = W2
// transpose into single bf16 plane. Block K1B additionally zeroes cursor.
// (R14-identical.)
// ---------------------------------------------------------------------------
__global__ __launch_bounds__(256) void kA(
    const int* __restrict__ cl, const float* __restrict__ W1,
    const float* __restrict__ W2, float* __restrict__ S1p,
    float* __restrict__ cntp, int* __restrict__ inv,
    unsigned short* __restrict__ W2Ph, int* __restrict__ cursor) {
  __shared__ float smem[64 * 65];              // 16.6 KB; segsum uses 2600
  int t = threadIdx.x;
  if (blockIdx.x < K1B) {
    // ---- segsum ----
    float (*s1)[N_CLUSTERS][N_D] = (float (*)[N_CLUSTERS][N_D])smem;
    float (*scnt)[N_CLUSTERS] =
        (float (*)[N_CLUSTERS])(smem + 4 * N_CLUSTERS * N_D);
    int wave = t >> 6, lane = t & 63;

    inv[blockIdx.x * 256 + t] = 0;             // zero all MAXT*16 slots

    float a[N_CLUSTERS], cn[N_CLUSTERS];
#pragma unroll
    for (int k = 0; k < N_CLUSTERS; ++k) { a[k] = 0.f; cn[k] = 0.f; }

    int gw = blockIdx.x * 4 + wave;
    int r0 = gw * 64;
#pragma unroll 1
    for (int b = 0; b < 8; ++b) {
      int i0 = r0 + b * 8;
      float w[8];
      int c[8];
      if (i0 + 8 <= N_ITEMS) {
#pragma unroll
        for (int j = 0; j < 8; ++j) {
          c[j] = cl[i0 + j];                   // wave-uniform -> s_load
          w[j] = W1[(size_t)(i0 + j) * N_D + lane];
        }
      } else {
#pragma unroll
        for (int j = 0; j < 8; ++j) {
          int i = i0 + j;
          bool ok = i < N_ITEMS;
          c[j] = ok ? cl[i] : -1;
          w[j] = ok ? W1[(size_t)i * N_D + lane] : 0.f;
        }
      }
#pragma unroll
      for (int j = 0; j < 8; ++j)
#pragma unroll
        for (int k = 0; k < N_CLUSTERS; ++k) {
          bool m = (c[j] == k);
          a[k] += m ? w[j] : 0.f;
          cn[k] += m ? 1.f : 0.f;
        }
    }
#pragma unroll
    for (int k = 0; k < N_CLUSTERS; ++k) s1[wave][k][lane] = a[k];
    if (lane == 0) {
#pragma unroll
      for (int k = 0; k < N_CLUSTERS; ++k) scnt[wave][k] = cn[k];
    }
    __syncthreads();
    const float* fs1 = smem;
    for (int i = t; i < N_CLUSTERS * N_D; i += 256) {
      S1p[blockIdx.x * 640 + i] =
          fs1[i] + fs1[640 + i] + fs1[1280 + i] + fs1[1920 + i];
    }
    if (t < N_CLUSTERS) {
      cntp[blockIdx.x * N_CLUSTERS + t] =
          scnt[0][t] + scnt[1][t] + scnt[2][t] + scnt[3][t];
    }
  } else {
    if (blockIdx.x == K1B && t < 16) cursor[t] = 0;
    // ---- w2p: transpose + single-plane bf16 ----
    float (*tile)[65] = (float (*)[65])smem;   // +1 pad: conflict-free
    int blk = blockIdx.x - K1B;
    int c0 = blk * 64;
    int cl_ = t & 63;
    int r0 = t >> 6;
    bool okr = (c0 + cl_) < N_ITEMS;
#pragma unroll
    for (int rr = 0; rr < 16; ++rr) {
      int r = rr * 4 + r0;
      tile[cl_][r] = okr ? W2[(size_t)r * N_ITEMS + c0 + cl_] : 0.f;
    }
    __syncthreads();
#pragma unroll
    for (int itw = 0; itw < 8; ++itw) {
      int task = itw * 256 + t;                // 2048 tasks: (col, dpair)
      int c_l = task >> 5, dp = task & 31;
      int c = c0 + c_l;
      if (c < N_ITEMS) {
        unsigned short h0 = bf16_rne(tile[c_l][dp * 2]);
        unsigned short h1 = bf16_rne(tile[c_l][dp * 2 + 1]);
        ((unsigned*)W2Ph)[(size_t)c * 32 + dp] =
            (unsigned)h0 | ((unsigned)h1 << 16);
      }
    }
  }
}

// ---------------------------------------------------------------------------
// Kernel M (402 blocks) — R14-identical:
//   blocks [0,10): S1g reduce; block 10: count reduce + tinfo + k3done=0;
//   blocks [11,402): inverse perm + bucket zero (self-computed baseS —
//   integer-valued float sums are order-exact).
// ---------------------------------------------------------------------------
__global__ __launch_bounds__(256) void kM(
    const int* __restrict__ cl, const float* __restrict__ S1p,
    const float* __restrict__ cntp, float* __restrict__ S1g,
    float* __restrict__ cntF, int* __restrict__ tinfo,
    int* __restrict__ cursor, int* __restrict__ inv,
    float* __restrict__ bucket, int* __restrict__ k3done) {
  int t = threadIdx.x;
  int wave = t >> 6, lane = t & 63;
  if (blockIdx.x < 10) {                       // ---- S1g chunk reduce ----
    __shared__ float sgp[4][64];
    int col = blockIdx.x * 64 + lane;
    float s = 0.f;
    const float* sp = S1p + col;
#pragma unroll 4
    for (int b = wave; b < K1B; b += 4) s += sp[b * 640];
    sgp[wave][lane] = s;
    __syncthreads();
    if (t < 64) {
      S1g[blockIdx.x * 64 + t] =
          sgp[0][t] + sgp[1][t] + sgp[2][t] + sgp[3][t];
    }
    return;
  }
  // shared count-reduce (blocks 10..401 all need cntI)
  __shared__ float part[16][N_CLUSTERS];
  __shared__ int cntIs[N_CLUSTERS];
  if (t < 160) {                               // coalesced count reduce
    int c = t % N_CLUSTERS, g = t / N_CLUSTERS;
    float s = 0.f;
    for (int b = g; b < K1B; b += 16) s += cntp[b * N_CLUSTERS + c];
    part[g][c] = s;
  }
  __syncthreads();
  if (t < N_CLUSTERS) {
    float s = 0.f;
#pragma unroll
    for (int g = 0; g < 16; ++g) s += part[g][t];
    cntIs[t] = (int)(s + 0.5f);
    if (blockIdx.x == 10) cntF[t] = s;
  }
  __syncthreads();
  int baseS[11];
  {
    int acc = 0;
#pragma unroll
    for (int c = 0; c < N_CLUSTERS; ++c) {
      baseS[c] = acc;
      acc += ((cntIs[c] + 15) >> 4) << 4;      // 16-align each segment
    }
    baseS[10] = acc;
  }
  if (blockIdx.x == 10) {                      // ---- tinfo table ----
    if (t == 0) *k3done = 0;
    int NT = baseS[10] >> 4;
    for (int jt = t; jt < MAXT; jt += 256) {
      int c = 0, nv = 0;
      if (jt < NT) {
        int p0 = jt * 16;
        for (int k = 0; k < N_CLUSTERS; ++k)
          if (p0 >= baseS[k] && p0 < baseS[k + 1]) c = k;
        nv = min(16, cntIs[c] - (p0 - baseS[c]));
        if (nv < 0) nv = 0;
      }
      tinfo[jt] = c | (nv << 8);
    }
    return;
  }
  // ---- perm + bucket zero ----
  __shared__ int wn[4][N_CLUSTERS];
  __shared__ int bb[N_CLUSTERS];
  int vb = blockIdx.x - 11;                    // 0..390
  int i = vb * 256 + t;
  if (i < N_B * N_CLUSTERS) bucket[i] = 0.f;
  int c = (i < N_ITEMS) ? cl[i] : -1;
  unsigned long long m[N_CLUSTERS];
#pragma unroll
  for (int k = 0; k < N_CLUSTERS; ++k) {
    m[k] = __ballot(c == k);
    if (lane == 0) wn[wave][k] = __popcll(m[k]);
  }
  __syncthreads();
  if (t < N_CLUSTERS) {
    int tot = wn[0][t] + wn[1][t] + wn[2][t] + wn[3][t];
    bb[t] = tot ? atomicAdd(&cursor[t], tot) : 0;
  }
  __syncthreads();
  if (c >= 0) {
    int rank = 0;
#pragma unroll
    for (int k = 0; k < N_CLUSTERS; ++k)
      if (c == k) rank = __popcll(m[k] & ((1ull << lane) - 1ull));
    int wsum = 0;
    for (int w2 = 0; w2 < wave; ++w2) wsum += wn[w2][c];
    inv[baseS[c] + bb[c] + wsum + rank] = i;
  }
}

// ---------------------------------------------------------------------------
// Kernel 3 (hot) — R15: 128-ROW wave-tiles. Scaling law from R6/R8/R13/R14:
// cyc/visit ≈ 1200-1500 INDEPENDENT of per-visit MFMA count (12/24/8 MFMA
// all the same) -> time ∝ visit count. Doubling the tile halves visits
// (100352 -> 50176). fr[16] + acc[8] + 2 B-bufs ≈ 140-reg working set ->
// (256,3) (the R8-proven cap=170 point, NOT R5's overflow). Grid 8x96=768.
// Prologue/tail from R14 (cooperative A-frag build; no-wbl2 done-counter).
// ---------------------------------------------------------------------------
__global__ __launch_bounds__(256, 3) void k3_mfma(
    const unsigned short* __restrict__ W2Ph, const float* __restrict__ inp,
    const float* __restrict__ S1g, const int* __restrict__ inv,
    const int* __restrict__ tinfo, float* __restrict__ bucket,
    const float* __restrict__ cntF, float* __restrict__ out,
    int* __restrict__ k3done) {
  __shared__ int linv[4][288];                 // 17*16=272 used, 4.6 KB
  __shared__ float stg[1920];                  // 7.7 KB: inp 128x10 + S1g
  __shared__ short8 frl[16][64];               // 16 KB fragment relay
  __shared__ int tk;
  int t = threadIdx.x;
  int wave = t >> 6, lane = t & 63;
  int l15 = lane & 15, quad = lane >> 4;

  // bijective XCD swizzle: 768 = 8 XCDs x 96
  int lid = blockIdx.y * 8 + blockIdx.x;
  int nid = (lid & 7) * 96 + (lid >> 3);
  int bx = nid & 7, by = nid >> 3;             // bx 0..7, by 0..95

  int gw = by * 4 + wave;                      // 0..383
  int jt0 = (MAXT * gw) / NGW;
  int nt = (MAXT * (gw + 1)) / NGW - jt0;      // 16 or 17

  // ---- prologue: stage + cooperative fragment build (16 frags) ----
  {
    const float* ip0 = inp + bx * 128 * N_CLUSTERS;  // 1280 floats
    for (int i = t; i < 1280; i += 256) stg[i] = ip0[i];
    for (int i = t; i < 640; i += 256) stg[1280 + i] = S1g[i];
    const int* ip = inv + jt0 * 16;
    int n = nt * 16;
    for (int i = lane; i < n; i += 64) linv[wave][i] = ip[i];
  }
  int tiv = tinfo[jt0 + ((lane < nt) ? lane : nt - 1)];
  __syncthreads();
  for (int id = t; id < 1024; id += 256) {     // 4 tuples/thread
    int lane2 = id & 63, f = id >> 6;          // f = rt*2+ks, rt 0..7
    int rt = f >> 1, ks = f & 1;
    int rowl = rt * 16 + (lane2 & 15);
    int d0 = ks * 32 + (lane2 >> 4) * 8;
    float hv[8];
#pragma unroll
    for (int j = 0; j < 8; ++j) hv[j] = 0.f;
#pragma unroll
    for (int c = 0; c < N_CLUSTERS; ++c) {
      float ic = stg[rowl * N_CLUSTERS + c];
      const float* sp = &stg[1280 + c * N_D + d0];
#pragma unroll
      for (int j = 0; j < 8; ++j) hv[j] += ic * sp[j];
    }
    short8 hi8;
#pragma unroll
    for (int j = 0; j < 8; ++j) {
      float x = hv[j] * 1.44269504088896340736f;   // fold log2(e) -> exp2
      hi8[j] = (short)bf16_rne(x);
    }
    frl[f][lane2] = hi8;
  }
  __syncthreads();
  short8 fr[16];
#pragma unroll
  for (int f = 0; f < 16; ++f) fr[f] = frl[f][lane];

  f32x4 acc[8];
#pragma unroll
  for (int r = 0; r < 8; ++r) acc[r] = (f32x4){0.f, 0.f, 0.f, 0.f};

  short8 xh0, xh1, yh0, yh1;
  int cc, nv, colN;
  {
    int c0 = linv[wave][l15];
    int o = c0 * 64 + quad * 8;
    xh0 = *(const short8*)(W2Ph + o);
    xh1 = *(const short8*)(W2Ph + o + 32);
    colN = linv[wave][16 + l15];               // tile 1 (nt >= 16 always)
    int ti = __builtin_amdgcn_readlane(tiv, 0);
    cc = ti & 255;
    nv = ti >> 8;
  }

#define K3_FLUSH()                                                            \
  {                                                                           \
    _Pragma("unroll") for (int rt = 0; rt < 8; ++rt) {                        \
      float e0 = acc[rt][0], e1 = acc[rt][1];                                 \
      float e2 = acc[rt][2], e3 = acc[rt][3];                                 \
      _Pragma("unroll") for (int mm = 1; mm < 16; mm <<= 1) {                 \
        e0 += __shfl_xor(e0, mm, 64);                                         \
        e1 += __shfl_xor(e1, mm, 64);                                         \
        e2 += __shfl_xor(e2, mm, 64);                                         \
        e3 += __shfl_xor(e3, mm, 64);                                         \
      }                                                                       \
      if (l15 == 0) {                                                         \
        int r = bx * 128 + rt * 16 + quad * 4;                                \
        atomicAdd(&bucket[(r + 0) * N_CLUSTERS + cc], e0);                    \
        atomicAdd(&bucket[(r + 1) * N_CLUSTERS + cc], e1);                    \
        atomicAdd(&bucket[(r + 2) * N_CLUSTERS + cc], e2);                    \
        atomicAdd(&bucket[(r + 3) * N_CLUSTERS + cc], e3);                    \
      }                                                                       \
      acc[rt] = (f32x4){0.f, 0.f, 0.f, 0.f};                                  \
    }                                                                         \
  }

#define K3_PHASE(CH0, CH1, NH0, NH1)                                          \
  {                                                                           \
    int tin = __builtin_amdgcn_readlane(tiv, (it + 1 < nt) ? it + 1 : nt - 1);\
    int ccn = tin & 255, nvn = tin >> 8;                                      \
    {                                                                         \
      int o = colN * 64 + quad * 8;            /* prefetch tile it+1 */       \
      NH0 = *(const short8*)(W2Ph + o);                                       \
      NH1 = *(const short8*)(W2Ph + o + 32);                                  \
    }                                                                         \
    colN = linv[wave][((it + 2 < nt) ? it + 2 : nt - 1) * 16 + l15];          \
    if (nv == 16) {                                                           \
      _Pragma("unroll") for (int rt = 0; rt < 8; ++rt) {                      \
        f32x4 c = {0.f, 0.f, 0.f, 0.f};                                       \
        c = MFMA(fr[rt * 2 + 0], CH0, c);                                     \
        c = MFMA(fr[rt * 2 + 1], CH1, c);                                     \
        acc[rt][0] += EXP2F(c[0]);                                            \
        acc[rt][1] += EXP2F(c[1]);                                            \
        acc[rt][2] += EXP2F(c[2]);                                            \
        acc[rt][3] += EXP2F(c[3]);                                            \
      }                                                                       \
    } else {                                                                  \
      _Pragma("unroll") for (int rt = 0; rt < 8; ++rt) {                      \
        f32x4 c = {0.f, 0.f, 0.f, 0.f};                                       \
        c = MFMA(fr[rt * 2 + 0], CH0, c);                                     \
        c = MFMA(fr[rt * 2 + 1], CH1, c);                                     \
        acc[rt][0] += (l15 < nv) ? EXP2F(c[0]) : 0.f;                         \
        acc[rt][1] += (l15 < nv) ? EXP2F(c[1]) : 0.f;                         \
        acc[rt][2] += (l15 < nv) ? EXP2F(c[2]) : 0.f;                         \
        acc[rt][3] += (l15 < nv) ? EXP2F(c[3]) : 0.f;                         \
      }                                                                       \
    }                                                                         \
    if (it == nt - 1 || ccn != cc) K3_FLUSH();                                \
    cc = ccn;                                                                 \
    nv = nvn;                                                                 \
    ++it;                                                                     \
    if (it == nt) break;                                                      \
  }

  int it = 0;
  while (true) {
    K3_PHASE(xh0, xh1, yh0, yh1)
    K3_PHASE(yh0, yh1, xh0, xh1)
  }
#undef K3_PHASE
#undef K3_FLUSH

  // ---- tail: no-wbl2 done-counter finalize ----
  asm volatile("s_waitcnt vmcnt(0)" ::: "memory");  // release: atomics ACK'd
  __syncthreads();
  if (t == 0) tk = atomicAdd(k3done, 1);
  __syncthreads();
  if (tk == NBLK3 - 1) {                       // last block finalizes
    for (int r = t; r < N_B; r += 256) {       // 4 rows/thread
      float v[N_CLUSTERS];
      float tot = 0.f;
#pragma unroll
      for (int k = 0; k < N_CLUSTERS; ++k) {
        v[k] = atomicAdd(&bucket[r * N_CLUSTERS + k], 0.0f);  // coherent read
        tot += v[k];
      }
#pragma unroll
      for (int k = 0; k < N_CLUSTERS; ++k)
        out[r * N_CLUSTERS + k] = v[k] / (tot * fmaxf(cntF[k], 1.f));
    }
    if (t == 0) *k3done = 0;                   // self-reset (kM also zeroes)
  }
}

// ---------------------------------------------------------------------------
// Workspace layout (4-byte units):
//   [0,640) S1g | [640,656) cntF | [672,688) cursor | [688) k3done
//   [1024,7296) tinfo = cluster|(nv<<8) | [16384,116736) inv
//   [262144,3463168) W2Ph (single bf16 plane, item-major)
//   [6664192,6915072) S1p | [6915072,6918992) cntp
//   [6918992,6929232) bucket (atomic accum; zeroed in kM)
// No memset: inv zeroed by kA, cursor by kA block K1B, bucket by kM,
// k3done by kM block 10 (+ k3 self-reset).
// ---------------------------------------------------------------------------
extern "C" void kernel_launch(void* const* d_in, const int* in_sizes, int n_in,
                              void* d_out, int out_size, void* d_ws, size_t ws_size,
                              hipStream_t stream) {
  const float* input = (const float*)d_in[0];   // (1024, 10) f32
  const int* cl      = (const int*)d_in[1];     // (100000,) i32
  const float* W1    = (const float*)d_in[2];   // (100000, 64) f32
  const float* W2    = (const float*)d_in[3];   // (64, 100000) f32
  float* out = (float*)d_out;
  float* ws = (float*)d_ws;

  float* S1g            = ws;
  float* cntF           = ws + 640;
  int*   cursor         = (int*)(ws + 672);
  int*   k3done         = (int*)(ws + 688);
  int*   tinfo          = (int*)(ws + 1024);
  int*   inv            = (int*)(ws + 16384);
  unsigned short* W2Ph  = (unsigned short*)(ws + 262144);
  float* S1p            = ws + 6664192;
  float* cntp           = ws + 6915072;
  float* bucket         = ws + 6918992;

  kA<<<K1B + W2PB, 256, 0, stream>>>(cl, W1, W2, S1p, cntp, inv, W2Ph,
                                     cursor);
  kM<<<402, 256, 0, stream>>>(cl, S1p, cntp, S1g, cntF, tinfo, cursor, inv,
                              bucket, k3done);
  dim3 g3(8, K3BY);                             // 768 blocks = 3/CU
  k3_mfma<<<g3, 256, 0, stream>>>(W2Ph, input, S1g, inv, tinfo, bucket,
                                  cntF, out, k3done);
}